// Round 25
// baseline (240.753 us; speedup 1.0000x reference)
//
#include <hip/hip_runtime.h>
#include <hip/hip_bf16.h>
#include <stdint.h>

// Problem constants
#define B_    2
#define S_    2048
#define HID_  2048
#define H_    16
#define KV_   2
#define D_    128
#define ROT_  32
#define QGS   4608   // combined qg|k|v row stride
#define SCALE_ 0.08838834764831845f  // D^-0.5
#define LOG2E_ 1.44269504f

typedef __attribute__((ext_vector_type(8))) short  short8;
typedef __attribute__((ext_vector_type(4))) float  floatx4;

__device__ __forceinline__ float b2f(unsigned short u) {
  union { unsigned int i; float f; } v; v.i = ((unsigned int)u) << 16; return v.f;
}
__device__ __forceinline__ unsigned short f2b(float f) {
  union { float f; unsigned int i; } v; v.f = f;
  return (unsigned short)((v.i + 0x7fffu + ((v.i >> 16) & 1u)) >> 16);
}
__device__ __forceinline__ void gload_lds16(const unsigned short* g, unsigned short* l) {
  __builtin_amdgcn_global_load_lds((const __attribute__((address_space(1))) void*)g,
                                   (__attribute__((address_space(3))) void*)l, 16, 0, 0);
}

// ---------------- fused preprocessing: prep | cvt(->fragment-major hbF) | 4 weight transposes ----------------
__device__ __forceinline__ void transpose_body(const float* __restrict__ in,
                                               unsigned short* __restrict__ out,
                                               int R, int C, int bx, int by, int t) {
  __shared__ unsigned short tile[64][68];
  int tx = t & 15, ty = t >> 4;
  long c0 = (long)bx * 64, r0 = (long)by * 64;
#pragma unroll
  for (int i = 0; i < 4; i++) {
    int row = ty + 16 * i;
    const float* src = in + (r0 + row) * C + c0 + 4 * tx;
    float4 v = *(const float4*)src;
    tile[row][4 * tx + 0] = f2b(v.x);
    tile[row][4 * tx + 1] = f2b(v.y);
    tile[row][4 * tx + 2] = f2b(v.z);
    tile[row][4 * tx + 3] = f2b(v.w);
  }
  __syncthreads();
#pragma unroll
  for (int i = 0; i < 4; i++) {
    int oc = ty + 16 * i;
    ushort4 v;
    v.x = tile[4 * tx + 0][oc];
    v.y = tile[4 * tx + 1][oc];
    v.z = tile[4 * tx + 2][oc];
    v.w = tile[4 * tx + 3][oc];
    *(ushort4*)(out + (c0 + oc) * R + r0 + 4 * tx) = v;
  }
}

__global__ __launch_bounds__(256) void k_preproc(const float* __restrict__ h_f,
                                                 const float* __restrict__ prior,
                                                 const float* __restrict__ Wq,
                                                 const float* __restrict__ Wk,
                                                 const float* __restrict__ Wv,
                                                 const float* __restrict__ Wo,
                                                 unsigned short* __restrict__ hbF,
                                                 unsigned short* __restrict__ WqkvT,
                                                 unsigned short* __restrict__ WoT,
                                                 float* __restrict__ ge,
                                                 float* __restrict__ kbias) {
  int bx = blockIdx.x;
  const int t = threadIdx.x;
  if (bx < 8) {
    int i = bx * 256 + t;
    float p  = prior[i];
    float pc = p * (float)S_;
    float g  = 1.0f + 0.1f * (pc - 1.0f);
    g = fminf(fmaxf(g, 0.9f), 1.1f);
    ge[i] = g;
    float cb = fminf(fmaxf(p, -3.0f), 3.0f);
    kbias[i] = (cb + logf(1.0f + 0.5f * pc)) * LOG2E_;  // log2-domain softmax
    return;
  }
  bx -= 8;
  if (bx < 4096) {  // cvt fp32 -> bf16, write FRAGMENT-MAJOR hbF
    long i0 = ((long)bx * 256 + t) * 8;
    float4 a = *(const float4*)(h_f + i0);
    float4 b = *(const float4*)(h_f + i0 + 4);
    short8 v;
    v[0] = (short)f2b(a.x); v[1] = (short)f2b(a.y);
    v[2] = (short)f2b(a.z); v[3] = (short)f2b(a.w);
    v[4] = (short)f2b(b.x); v[5] = (short)f2b(b.y);
    v[6] = (short)f2b(b.z); v[7] = (short)f2b(b.w);
    int row = (int)(i0 >> 11);
    int k   = (int)(i0 & 2047);
    size_t dst = ((size_t)((row >> 4) * 64 + (k >> 5))) * 512
               + (size_t)((row & 15) + ((k >> 3) & 3) * 16) * 8;
    *(short8*)(hbF + dst) = v;
    return;
  }
  bx -= 4096;
  if (bx < 2048) { transpose_body(Wq, WqkvT, 2048, 4096, bx & 63, bx >> 6, t); return; }
  bx -= 2048;
  if (bx < 1024) { transpose_body(Wo, WoT, 2048, 2048, bx & 31, bx >> 5, t); return; }
  bx -= 1024;
  if (bx < 128)  { transpose_body(Wk, WqkvT + (size_t)4096 * 2048, 2048, 256, bx & 3, bx >> 2, t); return; }
  bx -= 128;
  transpose_body(Wv, WqkvT + (size_t)4352 * 2048, 2048, 256, bx & 3, bx >> 2, t);
}

// ---------------- GEMM (A fragment-major from GLOBAL, B via LDS): C = A @ Bt^T ----------------
// BK=64 double-step: 4 LDS B-buffers (32 KB), ONE barrier + ONE vmcnt(8) per 2 K-steps.
// FUSEKV=1: blocks n0>=4352 apply eta -> fragment-major vF; blocks 4096<=n0<4352 apply
// full RMS+RoPE+gamma -> fragment-major kF (RoPE is register-local in the C layout;
// RMS row-sum = 4 shfl_xor over r15 + 1KB LDS cross-wave combine).
template <int OUT32, int FUSEKV>
__global__ __launch_bounds__(256, 4) void k_gemm_af(const unsigned short* __restrict__ aF,
                                                    const unsigned short* __restrict__ Bt,
                                                    void* __restrict__ Cv,
                                                    const float* __restrict__ geArr,
                                                    unsigned short* __restrict__ kFp,
                                                    unsigned short* __restrict__ vFp,
                                                    const float* __restrict__ knw,
                                                    const float* __restrict__ cosb,
                                                    const float* __restrict__ sinb,
                                                    int M, int N, int K) {
  __shared__ __align__(16) unsigned short Bs[4][128 * 32];
  __shared__ float ksum[2][2][64];
  const int t    = threadIdx.x;
  const int lane = t & 63;
  const int wv   = t >> 6;
  const int wm   = wv >> 1, wn = wv & 1;
  const long m0  = (long)blockIdx.y * 128;
  const long n0  = (long)blockIdx.x * 128;
  const int r15  = lane & 15, g4 = lane >> 4;

  const int srow = lane >> 2;
  const int scol = ((lane & 3) ^ ((lane >> 3) & 3)) * 8;  // inverse swizzle on global source
  const unsigned short* sB0 = Bt + (n0 + wv * 16 + srow)       * K + scol;
  const unsigned short* sB1 = Bt + (n0 + (wv + 4) * 16 + srow) * K + scol;

  const int KC = K >> 5;  // chunks per 16-row block
  const unsigned short* aBase = aF + ((size_t)(((m0 >> 4) + wm * 4) * KC)) * 512 + lane * 8;

  floatx4 acc[4][4];
#pragma unroll
  for (int m = 0; m < 4; m++)
#pragma unroll
    for (int n = 0; n < 4; n++) acc[m][n] = (floatx4){0.f, 0.f, 0.f, 0.f};

  const int nk = K >> 5;  // even
  gload_lds16(sB0,      &Bs[0][wv * 512]);
  gload_lds16(sB1,      &Bs[0][(wv + 4) * 512]);
  gload_lds16(sB0 + 32, &Bs[1][wv * 512]);
  gload_lds16(sB1 + 32, &Bs[1][(wv + 4) * 512]);
  __builtin_amdgcn_sched_barrier(0);
  short8 afA[4], afB[4];
#pragma unroll
  for (int m = 0; m < 4; m++) afA[m] = *(const short8*)(aBase + (size_t)(m * KC) * 512);
#pragma unroll
  for (int m = 0; m < 4; m++) afB[m] = *(const short8*)(aBase + (size_t)(m * KC + 1) * 512);
  __builtin_amdgcn_sched_barrier(0);

  const int fcol = (g4 ^ ((r15 >> 1) & 3)) * 8;  // swizzled B fragment read
  int rb = 0;
  for (int k = 0; k < nk; k += 2) {
    asm volatile("s_waitcnt vmcnt(8)" ::: "memory");
    __builtin_amdgcn_sched_barrier(0);
    __builtin_amdgcn_s_barrier();
    __builtin_amdgcn_sched_barrier(0);
    const bool more = (k + 2 < nk);
    if (more) {
      const int wb = rb ^ 2;
      gload_lds16(sB0 + (k + 2) * 32, &Bs[wb][wv * 512]);
      gload_lds16(sB1 + (k + 2) * 32, &Bs[wb][(wv + 4) * 512]);
      gload_lds16(sB0 + (k + 3) * 32, &Bs[wb + 1][wv * 512]);
      gload_lds16(sB1 + (k + 3) * 32, &Bs[wb + 1][(wv + 4) * 512]);
    }
    {
      short8 bf[4];
#pragma unroll
      for (int n = 0; n < 4; n++)
        bf[n] = *(const short8*)(&Bs[rb][(wn * 64 + n * 16 + r15) * 32 + fcol]);
#pragma unroll
      for (int m = 0; m < 4; m++)
#pragma unroll
        for (int n = 0; n < 4; n++)
          acc[m][n] = __builtin_amdgcn_mfma_f32_16x16x32_bf16(afA[m], bf[n], acc[m][n], 0, 0, 0);
    }
    if (more) {
#pragma unroll
      for (int m = 0; m < 4; m++)
        afA[m] = *(const short8*)(aBase + (size_t)(m * KC + k + 2) * 512);
    }
    {
      short8 bf[4];
#pragma unroll
      for (int n = 0; n < 4; n++)
        bf[n] = *(const short8*)(&Bs[rb + 1][(wn * 64 + n * 16 + r15) * 32 + fcol]);
#pragma unroll
      for (int m = 0; m < 4; m++)
#pragma unroll
        for (int n = 0; n < 4; n++)
          acc[m][n] = __builtin_amdgcn_mfma_f32_16x16x32_bf16(afB[m], bf[n], acc[m][n], 0, 0, 0);
    }
    if (more) {
#pragma unroll
      for (int m = 0; m < 4; m++)
        afB[m] = *(const short8*)(aBase + (size_t)(m * KC + k + 3) * 512);
    }
    rb ^= 2;
  }

  if (FUSEKV && n0 >= 4352) {
    // ---- fused v epilogue: out = acc * eta(row), written FRAGMENT-MAJOR to vF ----
    const int kvb = (int)((n0 - 4352) >> 7);
#pragma unroll
    for (int m = 0; m < 4; m++) {
      const int srow0 = (int)m0 + wm * 64 + m * 16 + g4 * 4;
#pragma unroll
      for (int i = 0; i < 4; i++) {
        const int srg = srow0 + i;
        const int bb = srg >> 11, s = srg & 2047;
        const float eta = geArr[s];
        const size_t base = (size_t)(bb * KV_ + kvb) * 262144;
#pragma unroll
        for (int n = 0; n < 4; n++) {
          const int d = wn * 64 + n * 16 + r15;
          size_t off = base
                     + (size_t)((s >> 6) * 16 + (d >> 4) * 2 + ((s >> 5) & 1)) * 512
                     + (size_t)((d & 15) + ((s >> 3) & 3) * 16) * 8 + (s & 7);
          vFp[off] = f2b(acc[m][n][i] * eta);
        }
      }
    }
    return;
  }

  if (FUSEKV && n0 >= 4096) {
    // ---- fused k epilogue: RMS (cross-lane+cross-wave) + RoPE (register-local) + gamma -> kF ----
    const int kvb = (int)((n0 - 4096) >> 7);
    float part[4][4];
#pragma unroll
    for (int m = 0; m < 4; m++)
#pragma unroll
      for (int i = 0; i < 4; i++) {
        float s2 = 0.f;
#pragma unroll
        for (int n = 0; n < 4; n++) s2 += acc[m][n][i] * acc[m][n][i];
        part[m][i] = s2;
      }
#pragma unroll
    for (int mask = 1; mask < 16; mask <<= 1)
#pragma unroll
      for (int m = 0; m < 4; m++)
#pragma unroll
        for (int i = 0; i < 4; i++)
          part[m][i] += __shfl_xor(part[m][i], mask);
    if (r15 == 0) {
#pragma unroll
      for (int m = 0; m < 4; m++)
#pragma unroll
        for (int i = 0; i < 4; i++)
          ksum[wm][wn][m * 16 + g4 * 4 + i] = part[m][i];
    }
    __syncthreads();
    float wn4[4];
#pragma unroll
    for (int n = 0; n < 4; n++) wn4[n] = knw[wn * 64 + n * 16 + r15];
#pragma unroll
    for (int m = 0; m < 4; m++) {
      const int lrow = m * 16 + g4 * 4;
#pragma unroll
      for (int i = 0; i < 4; i++) {
        float total = ksum[wm][0][lrow + i] + ksum[wm][1][lrow + i];
        float rstd = rsqrtf(total * (1.0f / 128.0f) + 1e-6f);
        const int srg = (int)m0 + wm * 64 + lrow + i;
        const int bb = srg >> 11, s = srg & 2047;
        const float gam = geArr[s];
        float xv[4];
#pragma unroll
        for (int n = 0; n < 4; n++) xv[n] = acc[m][n][i] * rstd * wn4[n];
        if (wn == 0) {  // RoPE region d<32: xv[0] (d=r15), xv[1] (d=16+r15) — same lane
          const float* cb = cosb + ((size_t)(bb * S_) + s) * ROT_;
          const float* sb = sinb + ((size_t)(bb * S_) + s) * ROT_;
          float c0 = cb[r15], c1 = cb[16 + r15];
          float s0 = sb[r15], s1 = sb[16 + r15];
          float y0 = xv[0] * c0 - xv[1] * s0;
          float y1 = xv[1] * c1 + xv[0] * s1;
          xv[0] = y0; xv[1] = y1;
        }
        const size_t base = (size_t)(bb * KV_ + kvb) * 262144;
#pragma unroll
        for (int n = 0; n < 4; n++) {
          const int d = wn * 64 + n * 16 + r15;
          size_t off = base
                     + (size_t)((s >> 4) * 4 + (d >> 5)) * 512
                     + (size_t)((s & 15) + ((d >> 3) & 3) * 16) * 8 + (d & 7);
          kFp[off] = f2b(xv[n] * gam);
        }
      }
    }
    return;
  }

#pragma unroll
  for (int m = 0; m < 4; m++) {
    const long rbase = m0 + wm * 64 + m * 16 + g4 * 4;
#pragma unroll
    for (int n = 0; n < 4; n++) {
      const long cidx = n0 + wn * 64 + n * 16 + r15;
#pragma unroll
      for (int i = 0; i < 4; i++) {
        if (OUT32) ((float*)Cv)[(rbase + i) * N + cidx] = acc[m][n][i];
        else ((unsigned short*)Cv)[(rbase + i) * N + cidx] = f2b(acc[m][n][i]);
      }
    }
  }
}

// ---------------- flash attention: 256-thr block = 4 waves = 4 strips of ONE head ----------------
// kbias folded into QK MFMA accumulator init; row-sum via ones-MFMA (C-layout lsum).
__global__ __launch_bounds__(256) void k_attn(const unsigned short* __restrict__ qgkv,
                                              const unsigned short* __restrict__ kF,
                                              const unsigned short* __restrict__ vF,
                                              const float* __restrict__ kbias,
                                              const float* __restrict__ cosb,
                                              const float* __restrict__ sinb,
                                              const float* __restrict__ qnw,
                                              unsigned short* __restrict__ agF) {
  __shared__ __align__(16) unsigned short KL[2][8192];   // 2 x 16 KB K tile
  __shared__ __align__(16) unsigned short Ps[4][16 * 88];
  const int t = threadIdx.x;
  const int lane = t & 63, wv = t >> 6;
  const int r15 = lane & 15, g4 = lane >> 4;
  const int p = blockIdx.x;
  const int xcd = p & 7;
  const int grp = xcd >> 1;
  const int mem = ((p >> 3) << 1) | (xcd & 1);
  const int head = mem & 7;
  const int quad = 31 - (mem >> 3);
  const int b = grp >> 1, kvh = grp & 1;
  const int hh = kvh * 8 + head;
  const int strip = quad * 4 + wv;
  const int q0s = strip * 16;
  const int ntiles = quad + 1;

  const unsigned short* kFg = kF + (size_t)(b * KV_ + kvh) * 262144;
  const unsigned short* vFg = vF + (size_t)(b * KV_ + kvh) * 262144;

  // ---- load q row (q0s + r15), RMS norm + RoPE in-register; fold SCALE*log2e into rstd ----
  short8 qf[4];
  {
    const int q = q0s + r15;
    const unsigned short* qp = qgkv + ((size_t)(b * S_) + q) * QGS + hh * 256 + g4 * 8;
    float xn[4][8];
    float ssq = 0.f;
#pragma unroll
    for (int kb = 0; kb < 4; kb++) {
      short8 qr = *(const short8*)(qp + kb * 32);
#pragma unroll
      for (int e = 0; e < 8; e++) {
        float x = b2f((unsigned short)qr[e]);
        xn[kb][e] = x;
        ssq += x * x;
      }
    }
    ssq += __shfl_xor(ssq, 16);
    ssq += __shfl_xor(ssq, 32);
    float rstd = rsqrtf(ssq * (1.0f / 128.0f) + 1e-6f) * (SCALE_ * LOG2E_);
#pragma unroll
    for (int kb = 0; kb < 4; kb++) {
      float4 w0 = *(const float4*)(&qnw[kb * 32 + g4 * 8]);
      float4 w1 = *(const float4*)(&qnw[kb * 32 + g4 * 8 + 4]);
      xn[kb][0] *= rstd * w0.x; xn[kb][1] *= rstd * w0.y;
      xn[kb][2] *= rstd * w0.z; xn[kb][3] *= rstd * w0.w;
      xn[kb][4] *= rstd * w1.x; xn[kb][5] *= rstd * w1.y;
      xn[kb][6] *= rstd * w1.z; xn[kb][7] *= rstd * w1.w;
    }
    {
      const float* cbp = cosb + ((size_t)(b * S_) + q) * ROT_ + g4 * 8;
      const float* sbp = sinb + ((size_t)(b * S_) + q) * ROT_ + g4 * 8;
      float4 c0 = *(const float4*)(cbp), c1 = *(const float4*)(cbp + 4);
      float4 s0 = *(const float4*)(sbp), s1 = *(const float4*)(sbp + 4);
      float cv[8] = {c0.x, c0.y, c0.z, c0.w, c1.x, c1.y, c1.z, c1.w};
      float sv[8] = {s0.x, s0.y, s0.z, s0.w, s1.x, s1.y, s1.z, s1.w};
      float sgn = (g4 < 2) ? -1.0f : 1.0f;
#pragma unroll
      for (int e = 0; e < 8; e++) {
        float part = __shfl_xor(xn[0][e], 32);
        xn[0][e] = xn[0][e] * cv[e] + sgn * part * sv[e];
      }
    }
#pragma unroll
    for (int kb = 0; kb < 4; kb++)
#pragma unroll
      for (int e = 0; e < 8; e++) qf[kb][e] = (short)f2b(xn[kb][e]);
  }

  floatx4 oacc[8];
#pragma unroll
  for (int nd = 0; nd < 8; nd++) oacc[nd] = (floatx4){0.f, 0.f, 0.f, 0.f};
  floatx4 lsum = (floatx4){0.f, 0.f, 0.f, 0.f};   // C-layout row sums (q = g4*4+i)
  float mrow = -1e30f;

  short8 onesB;
#pragma unroll
  for (int e = 0; e < 8; e++) onesB[e] = (short)0x3F80;

#pragma unroll
  for (int i = 0; i < 4; i++)
    gload_lds16(kFg + (size_t)wv * 2048 + i * 512 + lane * 8, &KL[0][wv * 2048 + i * 512]);
  __syncthreads();

  int cur = 0;
  for (int tile = 0; tile < ntiles; tile++) {
    if (tile + 1 < ntiles) {
      const size_t src = (size_t)(tile + 1) * 8192 + wv * 2048 + lane * 8;
#pragma unroll
      for (int i = 0; i < 4; i++)
        gload_lds16(kFg + src + i * 512, &KL[cur ^ 1][wv * 2048 + i * 512]);
    }

    const int j0 = tile * 64;
    floatx4 sacc[4];
#pragma unroll
    for (int n = 0; n < 4; n++) {
      float4 kb4 = *(const float4*)(&kbias[j0 + n * 16 + g4 * 4]);
      sacc[n] = (floatx4){kb4.x, kb4.y, kb4.z, kb4.w};
    }
    __builtin_amdgcn_s_setprio(1);
#pragma unroll
    for (int n = 0; n < 4; n++) {
      const unsigned short* kl = &KL[cur][n * 2048 + lane * 8];
      short8 a0 = *(const short8*)(kl);
      short8 a1 = *(const short8*)(kl + 512);
      short8 a2 = *(const short8*)(kl + 1024);
      short8 a3 = *(const short8*)(kl + 1536);
      sacc[n] = __builtin_amdgcn_mfma_f32_16x16x32_bf16(a0, qf[0], sacc[n], 0, 0, 0);
      sacc[n] = __builtin_amdgcn_mfma_f32_16x16x32_bf16(a1, qf[1], sacc[n], 0, 0, 0);
      sacc[n] = __builtin_amdgcn_mfma_f32_16x16x32_bf16(a2, qf[2], sacc[n], 0, 0, 0);
      sacc[n] = __builtin_amdgcn_mfma_f32_16x16x32_bf16(a3, qf[3], sacc[n], 0, 0, 0);
    }
    __builtin_amdgcn_s_setprio(0);

    const unsigned short* vt = vFg + (size_t)tile * 8192 + lane * 8;
    short8 vfA[8];
#pragma unroll
    for (int nd = 0; nd < 8; nd++) vfA[nd] = *(const short8*)(vt + (nd * 2) * 512);

    const bool last = (tile == ntiles - 1);
    float scf[4][4];
#pragma unroll
    for (int n = 0; n < 4; n++) {
#pragma unroll
      for (int i = 0; i < 4; i++) {
        float v = sacc[n][i];
        if (last) {
          int jg = j0 + n * 16 + g4 * 4 + i;
          if (jg > q0s + r15) v = -1e30f;
        }
        scf[n][i] = v;
      }
    }
    float pmax = scf[0][0];
#pragma unroll
    for (int n = 0; n < 4; n++)
#pragma unroll
      for (int i = 0; i < 4; i++) pmax = fmaxf(pmax, scf[n][i]);
    pmax = fmaxf(pmax, __shfl_xor(pmax, 16));
    pmax = fmaxf(pmax, __shfl_xor(pmax, 32));
    if (__any(pmax > mrow + 11.5f)) {
      float mn = fmaxf(mrow, pmax);
      float aq = exp2f(mrow - mn);
      mrow = mn;
      float ai[4];
#pragma unroll
      for (int i = 0; i < 4; i++) ai[i] = __shfl(aq, g4 * 4 + i);
#pragma unroll
      for (int i = 0; i < 4; i++) lsum[i] *= ai[i];
#pragma unroll
      for (int nd = 0; nd < 8; nd++)
#pragma unroll
        for (int i = 0; i < 4; i++) oacc[nd][i] *= ai[i];
    }
#pragma unroll
    for (int n = 0; n < 4; n++)
#pragma unroll
      for (int i = 0; i < 4; i++)
        scf[n][i] = exp2f(scf[n][i] - mrow);

#pragma unroll
    for (int n = 0; n < 4; n++) {
      unsigned int r0, r1;
      asm("v_cvt_pk_bf16_f32 %0, %1, %2" : "=v"(r0) : "v"(scf[n][0]), "v"(scf[n][1]));
      asm("v_cvt_pk_bf16_f32 %0, %1, %2" : "=v"(r1) : "v"(scf[n][2]), "v"(scf[n][3]));
      uint2 w; w.x = r0; w.y = r1;
      *(uint2*)(&Ps[wv][r15 * 88 + n * 16 + g4 * 4]) = w;
    }

    short8 vfB[8];
#pragma unroll
    for (int nd = 0; nd < 8; nd++) vfB[nd] = *(const short8*)(vt + (nd * 2 + 1) * 512);

    {
      __builtin_amdgcn_s_setprio(1);
      short8 pa0 = *(const short8*)(&Ps[wv][r15 * 88 + g4 * 8]);
#pragma unroll
      for (int nd = 0; nd < 8; nd++)
        oacc[nd] = __builtin_amdgcn_mfma_f32_16x16x32_bf16(pa0, vfA[nd], oacc[nd], 0, 0, 0);
      lsum = __builtin_amdgcn_mfma_f32_16x16x32_bf16(pa0, onesB, lsum, 0, 0, 0);
      short8 pa1 = *(const short8*)(&Ps[wv][r15 * 88 + 32 + g4 * 8]);
#pragma unroll
      for (int nd = 0; nd < 8; nd++)
        oacc[nd] = __builtin_amdgcn_mfma_f32_16x16x32_bf16(pa1, vfB[nd], oacc[nd], 0, 0, 0);
      lsum = __builtin_amdgcn_mfma_f32_16x16x32_bf16(pa1, onesB, lsum, 0, 0, 0);
      __builtin_amdgcn_s_setprio(0);
    }
    __syncthreads();
    cur ^= 1;
  }

  // ---- epilogue: gate + write FRAGMENT-MAJOR agF (lsum already in C-layout: q = g4*4+i) ----
  unsigned short* aBase = agF + (size_t)(b * 128 + strip) * 64 * 512;
#pragma unroll
  for (int i = 0; i < 4; i++) {
    int q = q0s + g4 * 4 + i;
    float inv = 1.0f / lsum[i];
    const unsigned short* gptr = qgkv + ((size_t)(b * S_ + q)) * QGS + hh * 256 + 128;
#pragma unroll
    for (int nd = 0; nd < 8; nd++) {
      int d = nd * 16 + r15;
      float gt = b2f(gptr[d]);
      float sg = 1.0f / (1.0f + __expf(-gt));
      size_t idx = (size_t)(hh * 4 + (d >> 5)) * 512
                 + (size_t)((g4 * 4 + i) + ((d >> 3) & 3) * 16) * 8 + (d & 7);
      aBase[idx] = f2b(oacc[nd][i] * inv * sg);
    }
  }
}

extern "C" void kernel_launch(void* const* d_in, const int* in_sizes, int n_in,
                              void* d_out, int out_size, void* d_ws, size_t ws_size,
                              hipStream_t stream) {
  const float* h_f   = (const float*)d_in[0];
  const float* cosb  = (const float*)d_in[1];
  const float* sinb  = (const float*)d_in[2];
  const float* prior = (const float*)d_in[4];
  const float* Wq    = (const float*)d_in[5];
  const float* Wk    = (const float*)d_in[6];
  const float* Wv    = (const float*)d_in[7];
  const float* Wo    = (const float*)d_in[8];
  const float* qnw   = (const float*)d_in[9];
  const float* knw   = (const float*)d_in[10];

  char* ws = (char*)d_ws;
  size_t off = 0;
  auto alloc = [&](size_t bytes) { char* p = ws + off; off += (bytes + 255) & ~(size_t)255; return p; };
  unsigned short* hbF   = (unsigned short*)alloc((size_t)4096 * 2048 * 2);  // fragment-major hidden states
  unsigned short* WqkvT = (unsigned short*)alloc((size_t)4608 * 2048 * 2);  // Wq|Wk|Wv transposed
  unsigned short* WoT   = (unsigned short*)alloc((size_t)2048 * 2048 * 2);
  unsigned short* qgkv  = (unsigned short*)alloc((size_t)4096 * QGS * 2);   // combined qg|k|v
  unsigned short* kF    = (unsigned short*)alloc((size_t)B_ * KV_ * S_ * D_ * 2);
  unsigned short* vF    = (unsigned short*)alloc((size_t)B_ * KV_ * S_ * D_ * 2);
  float* ge    = (float*)alloc((size_t)S_ * 4);
  float* kbias = (float*)alloc((size_t)S_ * 4);
  // Aliasing (sequential stream order): agF reuses hbF (dead after the projection GEMM).
  unsigned short* agF = hbF;

  dim3 blk(256);
  k_preproc<<<dim3(7432), blk, 0, stream>>>(h_f, prior, Wq, Wk, Wv, Wo,
                                            hbF, WqkvT, WoT, ge, kbias);
  k_gemm_af<0, 1><<<dim3(36, 32), blk, 0, stream>>>(hbF, WqkvT, qgkv, ge, kF, vF,
                                                    knw, cosb, sinb, 4096, QGS, 2048);
  k_attn<<<dim3(1024), blk, 0, stream>>>(qgkv, kF, vF, kbias, cosb, sinb, qnw, agF);
  k_gemm_af<1, 0><<<dim3(16, 32), blk, 0, stream>>>(agF, WoT, d_out, nullptr, nullptr, nullptr,
                                                    nullptr, nullptr, nullptr, 4096, 2048, 2048);
}

// Round 26
// 237.241 us; speedup vs baseline: 1.0148x; 1.0148x over previous
//
#include <hip/hip_runtime.h>
#include <hip/hip_bf16.h>
#include <stdint.h>

// Problem constants
#define B_    2
#define S_    2048
#define HID_  2048
#define H_    16
#define KV_   2
#define D_    128
#define ROT_  32
#define QGS   4608   // combined qg|k|v row stride
#define SCALE_ 0.08838834764831845f  // D^-0.5
#define LOG2E_ 1.44269504f

typedef __attribute__((ext_vector_type(8))) short  short8;
typedef __attribute__((ext_vector_type(4))) float  floatx4;

__device__ __forceinline__ float b2f(unsigned short u) {
  union { unsigned int i; float f; } v; v.i = ((unsigned int)u) << 16; return v.f;
}
__device__ __forceinline__ unsigned short f2b(float f) {
  union { float f; unsigned int i; } v; v.f = f;
  return (unsigned short)((v.i + 0x7fffu + ((v.i >> 16) & 1u)) >> 16);
}
__device__ __forceinline__ void gload_lds16(const unsigned short* g, unsigned short* l) {
  __builtin_amdgcn_global_load_lds((const __attribute__((address_space(1))) void*)g,
                                   (__attribute__((address_space(3))) void*)l, 16, 0, 0);
}

// ---------------- fused preprocessing: prep | cvt(->fragment-major hbF) | 4 weight transposes ----------------
__device__ __forceinline__ void transpose_body(const float* __restrict__ in,
                                               unsigned short* __restrict__ out,
                                               int R, int C, int bx, int by, int t) {
  __shared__ unsigned short tile[64][68];
  int tx = t & 15, ty = t >> 4;
  long c0 = (long)bx * 64, r0 = (long)by * 64;
#pragma unroll
  for (int i = 0; i < 4; i++) {
    int row = ty + 16 * i;
    const float* src = in + (r0 + row) * C + c0 + 4 * tx;
    float4 v = *(const float4*)src;
    tile[row][4 * tx + 0] = f2b(v.x);
    tile[row][4 * tx + 1] = f2b(v.y);
    tile[row][4 * tx + 2] = f2b(v.z);
    tile[row][4 * tx + 3] = f2b(v.w);
  }
  __syncthreads();
#pragma unroll
  for (int i = 0; i < 4; i++) {
    int oc = ty + 16 * i;
    ushort4 v;
    v.x = tile[4 * tx + 0][oc];
    v.y = tile[4 * tx + 1][oc];
    v.z = tile[4 * tx + 2][oc];
    v.w = tile[4 * tx + 3][oc];
    *(ushort4*)(out + (c0 + oc) * R + r0 + 4 * tx) = v;
  }
}

__global__ __launch_bounds__(256) void k_preproc(const float* __restrict__ h_f,
                                                 const float* __restrict__ prior,
                                                 const float* __restrict__ Wq,
                                                 const float* __restrict__ Wk,
                                                 const float* __restrict__ Wv,
                                                 const float* __restrict__ Wo,
                                                 unsigned short* __restrict__ hbF,
                                                 unsigned short* __restrict__ WqkvT,
                                                 unsigned short* __restrict__ WoT,
                                                 float* __restrict__ ge,
                                                 float* __restrict__ kbias) {
  int bx = blockIdx.x;
  const int t = threadIdx.x;
  if (bx < 8) {
    int i = bx * 256 + t;
    float p  = prior[i];
    float pc = p * (float)S_;
    float g  = 1.0f + 0.1f * (pc - 1.0f);
    g = fminf(fmaxf(g, 0.9f), 1.1f);
    ge[i] = g;
    float cb = fminf(fmaxf(p, -3.0f), 3.0f);
    kbias[i] = (cb + logf(1.0f + 0.5f * pc)) * LOG2E_;  // log2-domain softmax
    return;
  }
  bx -= 8;
  if (bx < 4096) {  // cvt fp32 -> bf16, write FRAGMENT-MAJOR hbF
    long i0 = ((long)bx * 256 + t) * 8;
    float4 a = *(const float4*)(h_f + i0);
    float4 b = *(const float4*)(h_f + i0 + 4);
    short8 v;
    v[0] = (short)f2b(a.x); v[1] = (short)f2b(a.y);
    v[2] = (short)f2b(a.z); v[3] = (short)f2b(a.w);
    v[4] = (short)f2b(b.x); v[5] = (short)f2b(b.y);
    v[6] = (short)f2b(b.z); v[7] = (short)f2b(b.w);
    int row = (int)(i0 >> 11);
    int k   = (int)(i0 & 2047);
    size_t dst = ((size_t)((row >> 4) * 64 + (k >> 5))) * 512
               + (size_t)((row & 15) + ((k >> 3) & 3) * 16) * 8;
    *(short8*)(hbF + dst) = v;
    return;
  }
  bx -= 4096;
  if (bx < 2048) { transpose_body(Wq, WqkvT, 2048, 4096, bx & 63, bx >> 6, t); return; }
  bx -= 2048;
  if (bx < 1024) { transpose_body(Wo, WoT, 2048, 2048, bx & 31, bx >> 5, t); return; }
  bx -= 1024;
  if (bx < 128)  { transpose_body(Wk, WqkvT + (size_t)4096 * 2048, 2048, 256, bx & 3, bx >> 2, t); return; }
  bx -= 128;
  transpose_body(Wv, WqkvT + (size_t)4352 * 2048, 2048, 256, bx & 3, bx >> 2, t);
}

// ---------------- GEMM (A fragment-major from GLOBAL, B via LDS): C = A @ Bt^T ----------------
// BK=64 double-step: 4 LDS B-buffers (32 KB), ONE barrier + ONE vmcnt(8) per 2 K-steps.
// FUSEV=1: blocks covering the v columns (n0 >= 4352) apply eta and write fragment-major vF
// directly (skipping the qgkv v-section round-trip).
template <int OUT32, int FUSEV>
__global__ __launch_bounds__(256, 4) void k_gemm_af(const unsigned short* __restrict__ aF,
                                                    const unsigned short* __restrict__ Bt,
                                                    void* __restrict__ Cv,
                                                    const float* __restrict__ geArr,
                                                    unsigned short* __restrict__ vFp,
                                                    int M, int N, int K) {
  __shared__ __align__(16) unsigned short Bs[4][128 * 32];
  const int t    = threadIdx.x;
  const int lane = t & 63;
  const int wv   = t >> 6;
  const int wm   = wv >> 1, wn = wv & 1;
  const long m0  = (long)blockIdx.y * 128;
  const long n0  = (long)blockIdx.x * 128;
  const int r15  = lane & 15, g4 = lane >> 4;

  const int srow = lane >> 2;
  const int scol = ((lane & 3) ^ ((lane >> 3) & 3)) * 8;  // inverse swizzle on global source
  const unsigned short* sB0 = Bt + (n0 + wv * 16 + srow)       * K + scol;
  const unsigned short* sB1 = Bt + (n0 + (wv + 4) * 16 + srow) * K + scol;

  const int KC = K >> 5;  // chunks per 16-row block
  const unsigned short* aBase = aF + ((size_t)(((m0 >> 4) + wm * 4) * KC)) * 512 + lane * 8;

  floatx4 acc[4][4];
#pragma unroll
  for (int m = 0; m < 4; m++)
#pragma unroll
    for (int n = 0; n < 4; n++) acc[m][n] = (floatx4){0.f, 0.f, 0.f, 0.f};

  const int nk = K >> 5;  // even
  gload_lds16(sB0,      &Bs[0][wv * 512]);
  gload_lds16(sB1,      &Bs[0][(wv + 4) * 512]);
  gload_lds16(sB0 + 32, &Bs[1][wv * 512]);
  gload_lds16(sB1 + 32, &Bs[1][(wv + 4) * 512]);
  __builtin_amdgcn_sched_barrier(0);
  short8 afA[4], afB[4];
#pragma unroll
  for (int m = 0; m < 4; m++) afA[m] = *(const short8*)(aBase + (size_t)(m * KC) * 512);
#pragma unroll
  for (int m = 0; m < 4; m++) afB[m] = *(const short8*)(aBase + (size_t)(m * KC + 1) * 512);
  __builtin_amdgcn_sched_barrier(0);

  const int fcol = (g4 ^ ((r15 >> 1) & 3)) * 8;  // swizzled B fragment read
  int rb = 0;
  for (int k = 0; k < nk; k += 2) {
    asm volatile("s_waitcnt vmcnt(8)" ::: "memory");
    __builtin_amdgcn_sched_barrier(0);
    __builtin_amdgcn_s_barrier();
    __builtin_amdgcn_sched_barrier(0);
    const bool more = (k + 2 < nk);
    if (more) {
      const int wb = rb ^ 2;
      gload_lds16(sB0 + (k + 2) * 32, &Bs[wb][wv * 512]);
      gload_lds16(sB1 + (k + 2) * 32, &Bs[wb][(wv + 4) * 512]);
      gload_lds16(sB0 + (k + 3) * 32, &Bs[wb + 1][wv * 512]);
      gload_lds16(sB1 + (k + 3) * 32, &Bs[wb + 1][(wv + 4) * 512]);
    }
    {
      short8 bf[4];
#pragma unroll
      for (int n = 0; n < 4; n++)
        bf[n] = *(const short8*)(&Bs[rb][(wn * 64 + n * 16 + r15) * 32 + fcol]);
#pragma unroll
      for (int m = 0; m < 4; m++)
#pragma unroll
        for (int n = 0; n < 4; n++)
          acc[m][n] = __builtin_amdgcn_mfma_f32_16x16x32_bf16(afA[m], bf[n], acc[m][n], 0, 0, 0);
    }
    if (more) {
#pragma unroll
      for (int m = 0; m < 4; m++)
        afA[m] = *(const short8*)(aBase + (size_t)(m * KC + k + 2) * 512);
    }
    {
      short8 bf[4];
#pragma unroll
      for (int n = 0; n < 4; n++)
        bf[n] = *(const short8*)(&Bs[rb + 1][(wn * 64 + n * 16 + r15) * 32 + fcol]);
#pragma unroll
      for (int m = 0; m < 4; m++)
#pragma unroll
        for (int n = 0; n < 4; n++)
          acc[m][n] = __builtin_amdgcn_mfma_f32_16x16x32_bf16(afB[m], bf[n], acc[m][n], 0, 0, 0);
    }
    if (more) {
#pragma unroll
      for (int m = 0; m < 4; m++)
        afB[m] = *(const short8*)(aBase + (size_t)(m * KC + k + 3) * 512);
    }
    rb ^= 2;
  }

  if (FUSEV && n0 >= 4352) {
    // ---- fused v epilogue: out = acc * eta(row), written FRAGMENT-MAJOR to vF ----
    const int kvb = (int)((n0 - 4352) >> 7);
#pragma unroll
    for (int m = 0; m < 4; m++) {
      const int srow0 = (int)m0 + wm * 64 + m * 16 + g4 * 4;
#pragma unroll
      for (int i = 0; i < 4; i++) {
        const int srg = srow0 + i;
        const int bb = srg >> 11, s = srg & 2047;
        const float eta = geArr[s];
        const size_t base = (size_t)(bb * KV_ + kvb) * 262144;
#pragma unroll
        for (int n = 0; n < 4; n++) {
          const int d = wn * 64 + n * 16 + r15;
          size_t off = base
                     + (size_t)((s >> 6) * 16 + (d >> 4) * 2 + ((s >> 5) & 1)) * 512
                     + (size_t)((d & 15) + ((s >> 3) & 3) * 16) * 8 + (s & 7);
          vFp[off] = f2b(acc[m][n][i] * eta);
        }
      }
    }
    return;
  }

#pragma unroll
  for (int m = 0; m < 4; m++) {
    const long rbase = m0 + wm * 64 + m * 16 + g4 * 4;
#pragma unroll
    for (int n = 0; n < 4; n++) {
      const long cidx = n0 + wn * 64 + n * 16 + r15;
#pragma unroll
      for (int i = 0; i < 4; i++) {
        if (OUT32) ((float*)Cv)[(rbase + i) * N + cidx] = acc[m][n][i];
        else ((unsigned short*)Cv)[(rbase + i) * N + cidx] = f2b(acc[m][n][i]);
      }
    }
  }
}

// ---------------- k postprocess (q inline in attn; v fused into the GEMM epilogue) ----------------
__global__ __launch_bounds__(256) void k_qkvpost(const unsigned short* __restrict__ qgkv,
                                                 const float* __restrict__ cosb,
                                                 const float* __restrict__ sinb,
                                                 const float* __restrict__ ge,
                                                 const float* __restrict__ knw,
                                                 unsigned short* __restrict__ kF) {
  int bxx = blockIdx.x;
  int wid  = bxx * 4 + ((int)threadIdx.x >> 6);   // 0..8191 over (b,s,kvb)
  int lane = threadIdx.x & 63;
  int kvb  = wid & 1;
  long bs  = wid >> 1;
  int b = (int)(bs >> 11), s = (int)(bs & 2047);
  int d0 = lane * 2;

  const unsigned short* src = qgkv + bs * QGS + 4096 + kvb * 128 + d0;
  float x0 = b2f(src[0]), x1 = b2f(src[1]);
  float ss = x0 * x0 + x1 * x1;
#pragma unroll
  for (int mask = 1; mask < 64; mask <<= 1) ss += __shfl_xor(ss, mask);
  float rstd = rsqrtf(ss * (1.0f / 128.0f) + 1e-6f);
  float w0 = knw[d0], w1 = knw[d0 + 1];
  float xn0 = x0 * rstd * w0, xn1 = x1 * rstd * w1;
  float p0 = __shfl_xor(xn0, 8), p1 = __shfl_xor(xn1, 8);
  float y0 = xn0, y1 = xn1;
  if (lane < 16) {
    float c0 = cosb[bs * ROT_ + d0], c1 = cosb[bs * ROT_ + d0 + 1];
    float s0 = sinb[bs * ROT_ + d0], s1 = sinb[bs * ROT_ + d0 + 1];
    float sgn = (lane < 8) ? -1.0f : 1.0f;
    y0 = xn0 * c0 + sgn * p0 * s0;
    y1 = xn1 * c1 + sgn * p1 * s1;
  }
  float g = ge[s];
  unsigned int pack = (unsigned int)f2b(y0 * g) | ((unsigned int)f2b(y1 * g) << 16);
  size_t off = (size_t)(b * KV_ + kvb) * 262144
             + (size_t)((s >> 4) * 4 + (d0 >> 5)) * 512
             + (size_t)(((s & 15) + (((d0 >> 3) & 3)) * 16)) * 8 + (d0 & 7);
  *(unsigned int*)(kF + off) = pack;
}

// ---------------- flash attention: 256-thr block = 4 waves = 4 strips of ONE head ----------------
// kbias folded into QK MFMA accumulator init; row-sum via ones-MFMA (C-layout lsum).
__global__ __launch_bounds__(256) void k_attn(const unsigned short* __restrict__ qgkv,
                                              const unsigned short* __restrict__ kF,
                                              const unsigned short* __restrict__ vF,
                                              const float* __restrict__ kbias,
                                              const float* __restrict__ cosb,
                                              const float* __restrict__ sinb,
                                              const float* __restrict__ qnw,
                                              unsigned short* __restrict__ agF) {
  __shared__ __align__(16) unsigned short KL[2][8192];   // 2 x 16 KB K tile
  __shared__ __align__(16) unsigned short Ps[4][16 * 88];
  const int t = threadIdx.x;
  const int lane = t & 63, wv = t >> 6;
  const int r15 = lane & 15, g4 = lane >> 4;
  const int p = blockIdx.x;
  const int xcd = p & 7;
  const int grp = xcd >> 1;
  const int mem = ((p >> 3) << 1) | (xcd & 1);
  const int head = mem & 7;
  const int quad = 31 - (mem >> 3);
  const int b = grp >> 1, kvh = grp & 1;
  const int hh = kvh * 8 + head;
  const int strip = quad * 4 + wv;
  const int q0s = strip * 16;
  const int ntiles = quad + 1;

  const unsigned short* kFg = kF + (size_t)(b * KV_ + kvh) * 262144;
  const unsigned short* vFg = vF + (size_t)(b * KV_ + kvh) * 262144;

  // ---- load q row (q0s + r15), RMS norm + RoPE in-register; fold SCALE*log2e into rstd ----
  short8 qf[4];
  {
    const int q = q0s + r15;
    const unsigned short* qp = qgkv + ((size_t)(b * S_) + q) * QGS + hh * 256 + g4 * 8;
    float xn[4][8];
    float ssq = 0.f;
#pragma unroll
    for (int kb = 0; kb < 4; kb++) {
      short8 qr = *(const short8*)(qp + kb * 32);
#pragma unroll
      for (int e = 0; e < 8; e++) {
        float x = b2f((unsigned short)qr[e]);
        xn[kb][e] = x;
        ssq += x * x;
      }
    }
    ssq += __shfl_xor(ssq, 16);
    ssq += __shfl_xor(ssq, 32);
    float rstd = rsqrtf(ssq * (1.0f / 128.0f) + 1e-6f) * (SCALE_ * LOG2E_);
#pragma unroll
    for (int kb = 0; kb < 4; kb++) {
      float4 w0 = *(const float4*)(&qnw[kb * 32 + g4 * 8]);
      float4 w1 = *(const float4*)(&qnw[kb * 32 + g4 * 8 + 4]);
      xn[kb][0] *= rstd * w0.x; xn[kb][1] *= rstd * w0.y;
      xn[kb][2] *= rstd * w0.z; xn[kb][3] *= rstd * w0.w;
      xn[kb][4] *= rstd * w1.x; xn[kb][5] *= rstd * w1.y;
      xn[kb][6] *= rstd * w1.z; xn[kb][7] *= rstd * w1.w;
    }
    {
      const float* cbp = cosb + ((size_t)(b * S_) + q) * ROT_ + g4 * 8;
      const float* sbp = sinb + ((size_t)(b * S_) + q) * ROT_ + g4 * 8;
      float4 c0 = *(const float4*)(cbp), c1 = *(const float4*)(cbp + 4);
      float4 s0 = *(const float4*)(sbp), s1 = *(const float4*)(sbp + 4);
      float cv[8] = {c0.x, c0.y, c0.z, c0.w, c1.x, c1.y, c1.z, c1.w};
      float sv[8] = {s0.x, s0.y, s0.z, s0.w, s1.x, s1.y, s1.z, s1.w};
      float sgn = (g4 < 2) ? -1.0f : 1.0f;
#pragma unroll
      for (int e = 0; e < 8; e++) {
        float part = __shfl_xor(xn[0][e], 32);
        xn[0][e] = xn[0][e] * cv[e] + sgn * part * sv[e];
      }
    }
#pragma unroll
    for (int kb = 0; kb < 4; kb++)
#pragma unroll
      for (int e = 0; e < 8; e++) qf[kb][e] = (short)f2b(xn[kb][e]);
  }

  floatx4 oacc[8];
#pragma unroll
  for (int nd = 0; nd < 8; nd++) oacc[nd] = (floatx4){0.f, 0.f, 0.f, 0.f};
  floatx4 lsum = (floatx4){0.f, 0.f, 0.f, 0.f};   // C-layout row sums (q = g4*4+i)
  float mrow = -1e30f;

  short8 onesB;
#pragma unroll
  for (int e = 0; e < 8; e++) onesB[e] = (short)0x3F80;

#pragma unroll
  for (int i = 0; i < 4; i++)
    gload_lds16(kFg + (size_t)wv * 2048 + i * 512 + lane * 8, &KL[0][wv * 2048 + i * 512]);
  __syncthreads();

  int cur = 0;
  for (int tile = 0; tile < ntiles; tile++) {
    if (tile + 1 < ntiles) {
      const size_t src = (size_t)(tile + 1) * 8192 + wv * 2048 + lane * 8;
#pragma unroll
      for (int i = 0; i < 4; i++)
        gload_lds16(kFg + src + i * 512, &KL[cur ^ 1][wv * 2048 + i * 512]);
    }

    const int j0 = tile * 64;
    floatx4 sacc[4];
#pragma unroll
    for (int n = 0; n < 4; n++) {
      float4 kb4 = *(const float4*)(&kbias[j0 + n * 16 + g4 * 4]);
      sacc[n] = (floatx4){kb4.x, kb4.y, kb4.z, kb4.w};
    }
    __builtin_amdgcn_s_setprio(1);
#pragma unroll
    for (int n = 0; n < 4; n++) {
      const unsigned short* kl = &KL[cur][n * 2048 + lane * 8];
      short8 a0 = *(const short8*)(kl);
      short8 a1 = *(const short8*)(kl + 512);
      short8 a2 = *(const short8*)(kl + 1024);
      short8 a3 = *(const short8*)(kl + 1536);
      sacc[n] = __builtin_amdgcn_mfma_f32_16x16x32_bf16(a0, qf[0], sacc[n], 0, 0, 0);
      sacc[n] = __builtin_amdgcn_mfma_f32_16x16x32_bf16(a1, qf[1], sacc[n], 0, 0, 0);
      sacc[n] = __builtin_amdgcn_mfma_f32_16x16x32_bf16(a2, qf[2], sacc[n], 0, 0, 0);
      sacc[n] = __builtin_amdgcn_mfma_f32_16x16x32_bf16(a3, qf[3], sacc[n], 0, 0, 0);
    }
    __builtin_amdgcn_s_setprio(0);

    const unsigned short* vt = vFg + (size_t)tile * 8192 + lane * 8;
    short8 vfA[8];
#pragma unroll
    for (int nd = 0; nd < 8; nd++) vfA[nd] = *(const short8*)(vt + (nd * 2) * 512);

    const bool last = (tile == ntiles - 1);
    float scf[4][4];
#pragma unroll
    for (int n = 0; n < 4; n++) {
#pragma unroll
      for (int i = 0; i < 4; i++) {
        float v = sacc[n][i];
        if (last) {
          int jg = j0 + n * 16 + g4 * 4 + i;
          if (jg > q0s + r15) v = -1e30f;
        }
        scf[n][i] = v;
      }
    }
    float pmax = scf[0][0];
#pragma unroll
    for (int n = 0; n < 4; n++)
#pragma unroll
      for (int i = 0; i < 4; i++) pmax = fmaxf(pmax, scf[n][i]);
    pmax = fmaxf(pmax, __shfl_xor(pmax, 16));
    pmax = fmaxf(pmax, __shfl_xor(pmax, 32));
    if (__any(pmax > mrow + 11.5f)) {
      float mn = fmaxf(mrow, pmax);
      float aq = exp2f(mrow - mn);
      mrow = mn;
      float ai[4];
#pragma unroll
      for (int i = 0; i < 4; i++) ai[i] = __shfl(aq, g4 * 4 + i);
#pragma unroll
      for (int i = 0; i < 4; i++) lsum[i] *= ai[i];
#pragma unroll
      for (int nd = 0; nd < 8; nd++)
#pragma unroll
        for (int i = 0; i < 4; i++) oacc[nd][i] *= ai[i];
    }
#pragma unroll
    for (int n = 0; n < 4; n++)
#pragma unroll
      for (int i = 0; i < 4; i++)
        scf[n][i] = exp2f(scf[n][i] - mrow);

#pragma unroll
    for (int n = 0; n < 4; n++) {
      unsigned int r0, r1;
      asm("v_cvt_pk_bf16_f32 %0, %1, %2" : "=v"(r0) : "v"(scf[n][0]), "v"(scf[n][1]));
      asm("v_cvt_pk_bf16_f32 %0, %1, %2" : "=v"(r1) : "v"(scf[n][2]), "v"(scf[n][3]));
      uint2 w; w.x = r0; w.y = r1;
      *(uint2*)(&Ps[wv][r15 * 88 + n * 16 + g4 * 4]) = w;
    }

    short8 vfB[8];
#pragma unroll
    for (int nd = 0; nd < 8; nd++) vfB[nd] = *(const short8*)(vt + (nd * 2 + 1) * 512);

    {
      __builtin_amdgcn_s_setprio(1);
      short8 pa0 = *(const short8*)(&Ps[wv][r15 * 88 + g4 * 8]);
#pragma unroll
      for (int nd = 0; nd < 8; nd++)
        oacc[nd] = __builtin_amdgcn_mfma_f32_16x16x32_bf16(pa0, vfA[nd], oacc[nd], 0, 0, 0);
      lsum = __builtin_amdgcn_mfma_f32_16x16x32_bf16(pa0, onesB, lsum, 0, 0, 0);
      short8 pa1 = *(const short8*)(&Ps[wv][r15 * 88 + 32 + g4 * 8]);
#pragma unroll
      for (int nd = 0; nd < 8; nd++)
        oacc[nd] = __builtin_amdgcn_mfma_f32_16x16x32_bf16(pa1, vfB[nd], oacc[nd], 0, 0, 0);
      lsum = __builtin_amdgcn_mfma_f32_16x16x32_bf16(pa1, onesB, lsum, 0, 0, 0);
      __builtin_amdgcn_s_setprio(0);
    }
    __syncthreads();
    cur ^= 1;
  }

  // ---- epilogue: gate + write FRAGMENT-MAJOR agF (lsum already in C-layout: q = g4*4+i) ----
  unsigned short* aBase = agF + (size_t)(b * 128 + strip) * 64 * 512;
#pragma unroll
  for (int i = 0; i < 4; i++) {
    int q = q0s + g4 * 4 + i;
    float inv = 1.0f / lsum[i];
    const unsigned short* gptr = qgkv + ((size_t)(b * S_ + q)) * QGS + hh * 256 + 128;
#pragma unroll
    for (int nd = 0; nd < 8; nd++) {
      int d = nd * 16 + r15;
      float gt = b2f(gptr[d]);
      float sg = 1.0f / (1.0f + __expf(-gt));
      size_t idx = (size_t)(hh * 4 + (d >> 5)) * 512
                 + (size_t)((g4 * 4 + i) + ((d >> 3) & 3) * 16) * 8 + (d & 7);
      aBase[idx] = f2b(oacc[nd][i] * inv * sg);
    }
  }
}

extern "C" void kernel_launch(void* const* d_in, const int* in_sizes, int n_in,
                              void* d_out, int out_size, void* d_ws, size_t ws_size,
                              hipStream_t stream) {
  const float* h_f   = (const float*)d_in[0];
  const float* cosb  = (const float*)d_in[1];
  const float* sinb  = (const float*)d_in[2];
  const float* prior = (const float*)d_in[4];
  const float* Wq    = (const float*)d_in[5];
  const float* Wk    = (const float*)d_in[6];
  const float* Wv    = (const float*)d_in[7];
  const float* Wo    = (const float*)d_in[8];
  const float* qnw   = (const float*)d_in[9];
  const float* knw   = (const float*)d_in[10];

  char* ws = (char*)d_ws;
  size_t off = 0;
  auto alloc = [&](size_t bytes) { char* p = ws + off; off += (bytes + 255) & ~(size_t)255; return p; };
  unsigned short* hbF   = (unsigned short*)alloc((size_t)4096 * 2048 * 2);  // fragment-major hidden states
  unsigned short* WqkvT = (unsigned short*)alloc((size_t)4608 * 2048 * 2);  // Wq|Wk|Wv transposed
  unsigned short* WoT   = (unsigned short*)alloc((size_t)2048 * 2048 * 2);
  unsigned short* qgkv  = (unsigned short*)alloc((size_t)4096 * QGS * 2);   // combined qg|k|v
  unsigned short* kF    = (unsigned short*)alloc((size_t)B_ * KV_ * S_ * D_ * 2);
  unsigned short* vF    = (unsigned short*)alloc((size_t)B_ * KV_ * S_ * D_ * 2);
  float* ge    = (float*)alloc((size_t)S_ * 4);
  float* kbias = (float*)alloc((size_t)S_ * 4);
  // Aliasing (sequential stream order): agF reuses hbF (dead after the projection GEMM).
  unsigned short* agF = hbF;

  dim3 blk(256);
  k_preproc<<<dim3(7432), blk, 0, stream>>>(h_f, prior, Wq, Wk, Wv, Wo,
                                            hbF, WqkvT, WoT, ge, kbias);
  k_gemm_af<0, 1><<<dim3(36, 32), blk, 0, stream>>>(hbF, WqkvT, qgkv, ge, vF, 4096, QGS, 2048);
  k_qkvpost<<<dim3(2048), blk, 0, stream>>>(qgkv, cosb, sinb, ge, knw, kF);
  k_attn<<<dim3(1024), blk, 0, stream>>>(qgkv, kF, vF, kbias, cosb, sinb, qnw, agF);
  k_gemm_af<1, 0><<<dim3(16, 32), blk, 0, stream>>>(agF, WoT, d_out, nullptr, nullptr, 4096, 2048, 2048);
}